// Round 2
// baseline (229.626 us; speedup 1.0000x reference)
//
#include <hip/hip_runtime.h>
#include <cstdint>
#include <cstddef>
#include <math.h>

#define BOX_W_C  5.0f
#define GIOU_W_C 2.0f
#define OBJ_W_C  1.0f
#define CLS_W_C  1.5f
#define CTR_W_C  0.5f
#define POS_RADIUS_C 1.0f
#define MAXM 128
#define BLK 256

// full focal element: a_t * ce * (1-p_t)^2, alpha=0.25, gamma=2, t in {0,1}
__device__ __forceinline__ float focal_elem(float x, float t) {
    float ax = fabsf(x);
    float e  = __expf(-ax);
    float lg = __logf(1.0f + e);              // log1p(exp(-|x|))
    float ce = fmaxf(x, 0.0f) - x * t + lg;
    float inv = 1.0f / (1.0f + e);
    float p  = (x >= 0.0f) ? inv : e * inv;   // sigmoid
    float p_t = p * t + (1.0f - p) * (1.0f - t);
    float a_t = 0.25f * t + 0.75f * (1.0f - t);
    float om  = 1.0f - p_t;
    return a_t * ce * om * om;
}

// negative-target focal (t = 0): 0.75 * (max(x,0)+log1p(e^-|x|)) * sigmoid(x)^2
__device__ __forceinline__ float focal_neg(float x) {
    float ax = fabsf(x);
    float e  = __expf(-ax);
    float lg = __logf(1.0f + e);
    float ce = fmaxf(x, 0.0f) + lg;
    float inv = 1.0f / (1.0f + e);
    float p  = (x >= 0.0f) ? inv : e * inv;
    return 0.75f * ce * p * p;
}

// focal(x, t=1) - focal(x, t=0), shared transcendentals
__device__ __forceinline__ float focal_pos_correction(float x) {
    float ax = fabsf(x);
    float e  = __expf(-ax);
    float lg = __logf(1.0f + e);
    float relu = fmaxf(x, 0.0f);
    float inv = 1.0f / (1.0f + e);
    float p  = (x >= 0.0f) ? inv : e * inv;
    float om = 1.0f - p;
    float f1 = 0.25f * (relu - x + lg) * om * om;
    float f0 = 0.75f * (relu + lg) * p * p;
    return f1 - f0;
}

__device__ __forceinline__ unsigned long long u64min(unsigned long long a,
                                                     unsigned long long b) {
    return (b < a) ? b : a;
}

// Kernel 1: one block per (b,m). Per-GT: box coords, area, has_candidate,
// fallback best location (first-occurrence argmin via packed (dist,idx) u64
// keys — nonneg float bits are order-monotone, low-32 index breaks ties to
// the smaller index = jnp.argmin first-occurrence semantics).
// Also zeroes the device "blocks done" counter used by kernel 2.
__global__ void gt_assign_kernel(const float* __restrict__ locations,
                                 const float* __restrict__ gt_boxes,
                                 const int* __restrict__ gh_p,
                                 const int* __restrict__ gw_p,
                                 int L, int M,
                                 float* __restrict__ info,
                                 int* __restrict__ flags,
                                 int* __restrict__ counter) {
    int bm  = blockIdx.x;
    int tid = threadIdx.x;

    if (bm == 0 && tid == 0) *counter = 0;   // stream-ordered before kernel 2

    const float* gb = gt_boxes + (size_t)bm * 4;
    float cx = gb[0], cy = gb[1], w = gb[2], h = gb[3];
    float x1 = cx - w * 0.5f, y1 = cy - h * 0.5f;
    float x2 = cx + w * 0.5f, y2 = cy + h * 0.5f;
    float area = w * h;
    float rx = POS_RADIUS_C / (float)gw_p[0];
    float ry = POS_RADIUS_C / (float)gh_p[0];

    unsigned long long k_in  = ~0ull;   // min over inside_box lanes
    unsigned long long k_all = ~0ull;   // unmasked min
    int any_cand = 0, any_in = 0;

    const float2* loc2 = (const float2*)locations;
    for (int l = tid; l < L; l += BLK) {
        float2 p2 = loc2[l];
        float lx = p2.x, ly = p2.y;
        bool inb = (lx > x1) && (ly > y1) && (lx < x2) && (ly < y2);
        bool inc = (fabsf(lx - cx) <= rx) && (fabsf(ly - cy) <= ry);
        any_cand |= (int)(inb && inc);
        any_in   |= (int)inb;
        float dx = lx - cx, dy = ly - cy;
        float dist = dx * dx + dy * dy;      // finite, nonneg
        unsigned long long kd =
            ((unsigned long long)__float_as_uint(dist) << 32) | (unsigned)l;
        k_all = u64min(k_all, kd);
        if (inb) k_in = u64min(k_in, kd);
    }

    // wave shuffle reduce (64 lanes), no barriers
    for (int off = 32; off > 0; off >>= 1) {
        unsigned long long o1 = __shfl_down(k_in,  off);
        unsigned long long o2 = __shfl_down(k_all, off);
        k_in  = u64min(k_in,  o1);
        k_all = u64min(k_all, o2);
        any_cand |= __shfl_down(any_cand, off);
        any_in   |= __shfl_down(any_in,   off);
    }

    __shared__ unsigned long long sk1[BLK / 64], sk2[BLK / 64];
    __shared__ int sc[BLK / 64], sn[BLK / 64];
    int wid = tid >> 6;
    if ((tid & 63) == 0) {
        sk1[wid] = k_in; sk2[wid] = k_all;
        sc[wid] = any_cand; sn[wid] = any_in;
    }
    __syncthreads();
    if (tid == 0) {
        for (int w2 = 1; w2 < BLK / 64; ++w2) {
            k_in  = u64min(k_in,  sk1[w2]);
            k_all = u64min(k_all, sk2[w2]);
            any_cand |= sc[w2];
            any_in   |= sn[w2];
        }
        int best = any_in ? (int)(k_in & 0xffffffffu) : (int)(k_all & 0xffffffffu);
        flags[bm * 2]     = any_cand;
        flags[bm * 2 + 1] = best;
        float* oi = info + (size_t)bm * 8;
        oi[0] = x1; oi[1] = y1; oi[2] = x2; oi[3] = y2;
        oi[4] = cx; oi[5] = cy; oi[6] = area; oi[7] = 0.0f;
    }
}

// Kernel 2 (fused): block = 256 consecutive locations of one batch image.
// Phase 1: per-location assignment + obj focal + box/GIoU/ctr losses.
// Phase 2: class focal = flat streaming sum of focal_neg over the block's
// contiguous 256*C logits. Plain cached loads: the 84 MB logits stream is
// Infinity-Cache-resident across graph replays (87 MB inputs < 256 MB LLC);
// nontemporal loads measured 4x slower (round 1: 80 us, 531 GB/s,
// latency-bound at 4 blocks/CU).
// Per-block partials stored to private slots; the LAST block (device-scope
// acq_rel counter) re-runs the finalize reduction in the exact same order
// as the old finalize_kernel (bitwise-identical result).
__global__ void fused_loss_kernel(const float* __restrict__ boxes_xyxy,
                                  const float* __restrict__ box_deltas,
                                  const float* __restrict__ class_logits,
                                  const float* __restrict__ objectness,
                                  const float* __restrict__ centerness,
                                  const float* __restrict__ locations,
                                  const int* __restrict__ gt_labels,
                                  const int* __restrict__ gh_p,
                                  const int* __restrict__ gw_p,
                                  int L, int M, int C, int bpb, int nblk,
                                  const float* __restrict__ info,
                                  const int* __restrict__ flags,
                                  float* __restrict__ partials,
                                  int* __restrict__ counter,
                                  float* __restrict__ out,
                                  float invBL, float invBLC) {
    __shared__ float s_x1[MAXM], s_y1[MAXM], s_x2[MAXM], s_y2[MAXM];
    __shared__ float s_cx[MAXM], s_cy[MAXM], s_area[MAXM];
    __shared__ int   s_lab[MAXM], s_hc[MAXM], s_best[MAXM];

    int b    = blockIdx.x / bpb;
    int lblk = blockIdx.x % bpb;
    int tid  = threadIdx.x;

    if (tid < M && tid < MAXM) {
        int bm = b * M + tid;
        const float* oi = info + (size_t)bm * 8;
        s_x1[tid] = oi[0]; s_y1[tid] = oi[1]; s_x2[tid] = oi[2]; s_y2[tid] = oi[3];
        s_cx[tid] = oi[4]; s_cy[tid] = oi[5]; s_area[tid] = oi[6];
        s_lab[tid]  = gt_labels[bm];
        s_hc[tid]   = flags[bm * 2];
        s_best[tid] = flags[bm * 2 + 1];
    }
    __syncthreads();

    int l0 = lblk * BLK;
    int l  = l0 + tid;
    float a_obj = 0.f, a_w = 0.f, a_l1 = 0.f, a_giou = 0.f, a_ctr = 0.f;
    float a_cls = 0.f;
    int mylab = -1;

    if (l < L) {
        size_t bl = (size_t)b * L + l;
        const float2* loc2 = (const float2*)locations;
        float2 p2 = loc2[l];
        float lx = p2.x, ly = p2.y;
        float rx = POS_RADIUS_C / (float)gw_p[0];
        float ry = POS_RADIUS_C / (float)gh_p[0];

        float minc = INFINITY;
        int   asg  = -1;
        for (int m = 0; m < M; ++m) {
            bool cand;
            if (s_hc[m]) {
                cand = (lx > s_x1[m]) && (ly > s_y1[m]) && (lx < s_x2[m]) && (ly < s_y2[m])
                    && (fabsf(lx - s_cx[m]) <= rx) && (fabsf(ly - s_cy[m]) <= ry);
            } else {
                cand = (l == s_best[m]);
            }
            if (cand && (s_area[m] < minc)) { minc = s_area[m]; asg = m; }  // first-min wins
        }
        bool  pos   = (asg >= 0);
        float pos_f = pos ? 1.0f : 0.0f;
        mylab = pos ? s_lab[asg] : -1;

        a_obj = focal_elem(objectness[bl], pos_f);

        if (pos) {
            float ax1 = s_x1[asg], ay1 = s_y1[asg], ax2 = s_x2[asg], ay2 = s_y2[asg];
            float ltl = fmaxf(lx - ax1, 1e-6f);
            float ltt = fmaxf(ly - ay1, 1e-6f);
            float ltr = fmaxf(ax2 - lx, 1e-6f);
            float ltb = fmaxf(ay2 - ly, 1e-6f);
            float hor = fminf(ltl, ltr) / fmaxf(fmaxf(ltl, ltr), 1e-6f);
            float ver = fminf(ltt, ltb) / fmaxf(fmaxf(ltt, ltb), 1e-6f);
            float ctr_t = sqrtf(fmaxf(hor * ver, 0.0f));
            float wgt = fmaxf(ctr_t, 0.1f);
            a_w = wgt;

            // smooth-L1 (beta = 0.1), mean over 4 coords
            const float4 bd = *(const float4*)(box_deltas + bl * 4);
            float d0 = fabsf(bd.x - ltl), d1 = fabsf(bd.y - ltt);
            float d2 = fabsf(bd.z - ltr), d3 = fabsf(bd.w - ltb);
            float l1s = ((d0 < 0.1f) ? (0.5f * d0 * d0 / 0.1f) : (d0 - 0.05f))
                      + ((d1 < 0.1f) ? (0.5f * d1 * d1 / 0.1f) : (d1 - 0.05f))
                      + ((d2 < 0.1f) ? (0.5f * d2 * d2 / 0.1f) : (d2 - 0.05f))
                      + ((d3 < 0.1f) ? (0.5f * d3 * d3 / 0.1f) : (d3 - 0.05f));
            a_l1 = (l1s * 0.25f) * wgt;

            // GIoU
            const float4 pb = *(const float4*)(boxes_xyxy + bl * 4);
            float px1 = pb.x, py1 = pb.y, px2 = pb.z, py2 = pb.w;
            float ilx = fmaxf(px1, ax1), ily = fmaxf(py1, ay1);
            float irx = fminf(px2, ax2), iry = fminf(py2, ay2);
            float iw = fmaxf(irx - ilx, 0.f), ih = fmaxf(iry - ily, 0.f);
            float inter = iw * ih;
            float ap = fmaxf(px2 - px1, 0.f) * fmaxf(py2 - py1, 0.f);
            float ag = fmaxf(ax2 - ax1, 0.f) * fmaxf(ay2 - ay1, 0.f);
            float un = ap + ag - inter;
            float iou = inter / fmaxf(un, 1e-6f);
            float hlx = fminf(px1, ax1), hly = fminf(py1, ay1);
            float hrx = fmaxf(px2, ax2), hry = fmaxf(py2, ay2);
            float hw = fmaxf(hrx - hlx, 0.f), hh = fmaxf(hry - hly, 0.f);
            float hull = hw * hh;
            float giou = iou - (hull - un) / fmaxf(hull, 1e-6f);
            a_giou = (1.0f - giou) * wgt;

            // centerness BCE
            float xc = centerness[bl];
            float bce = fmaxf(xc, 0.f) - xc * ctr_t + __logf(1.0f + __expf(-fabsf(xc)));
            a_ctr = bce * wgt;
        }

        // positive-class correction for this thread's own row (rare path)
        if (mylab >= 0) {
            float xl = class_logits[bl * (size_t)C + mylab];
            a_cls += focal_pos_correction(xl);
        }
    }

    // Phase 2: flat streaming focal_neg over rows [l0, l0+nrows) x C.
    {
        int nrows = L - l0; if (nrows > BLK) nrows = BLK;
        int C4 = C >> 2;
        if (C4 > 0) {
            const float4* cl4 = (const float4*)(class_logits + ((size_t)b * L + l0) * C);
            int total4 = nrows * C4;
            for (int it = tid; it < total4; it += BLK) {
                float4 v = cl4[it];
                a_cls += focal_neg(v.x);
                a_cls += focal_neg(v.y);
                a_cls += focal_neg(v.z);
                a_cls += focal_neg(v.w);
            }
        }
        int crem = C - (C4 << 2);              // leftover classes (C % 4) — rare path
        if (crem) {
            const float* base = class_logits + ((size_t)b * L + l0) * C + (C4 << 2);
            for (int rr = tid; rr < nrows; rr += BLK)
                for (int j = 0; j < crem; ++j)
                    a_cls += focal_neg(base[(size_t)rr * C + j]);
        }
    }

    // wave shuffle reduce, LDS across waves, thread 0 stores 6 partials
    for (int off = 32; off > 0; off >>= 1) {
        a_obj  += __shfl_down(a_obj,  off);
        a_w    += __shfl_down(a_w,    off);
        a_l1   += __shfl_down(a_l1,   off);
        a_giou += __shfl_down(a_giou, off);
        a_ctr  += __shfl_down(a_ctr,  off);
        a_cls  += __shfl_down(a_cls,  off);
    }
    __shared__ float red[BLK / 64][6];
    __shared__ int s_last;
    int wid = tid >> 6;
    if ((tid & 63) == 0) {
        red[wid][0] = a_obj; red[wid][1] = a_w; red[wid][2] = a_l1;
        red[wid][3] = a_giou; red[wid][4] = a_ctr; red[wid][5] = a_cls;
    }
    __syncthreads();
    if (tid == 0) {
        float r0 = 0.f, r1 = 0.f, r2 = 0.f, r3 = 0.f, r4 = 0.f, r5 = 0.f;
        for (int w2 = 0; w2 < BLK / 64; ++w2) {
            r0 += red[w2][0]; r1 += red[w2][1]; r2 += red[w2][2];
            r3 += red[w2][3]; r4 += red[w2][4]; r5 += red[w2][5];
        }
        int blk = (int)blockIdx.x;
        partials[0 * nblk + blk] = r0;   // obj
        partials[1 * nblk + blk] = r1;   // wsum
        partials[2 * nblk + blk] = r2;   // l1
        partials[3 * nblk + blk] = r3;   // giou
        partials[4 * nblk + blk] = r4;   // ctr
        partials[5 * nblk + blk] = r5;   // cls
        // release: prior plain stores drained to coherence point, then count.
        int done = __hip_atomic_fetch_add(counter, 1, __ATOMIC_ACQ_REL,
                                          __HIP_MEMORY_SCOPE_AGENT);
        s_last = (done == nblk - 1) ? 1 : 0;
    }
    __syncthreads();
    if (!s_last) return;

    // ---- last block: finalize (same order as old finalize_kernel) ----
    __threadfence();   // acquire for all lanes: invalidate stale L1/L2 lines
    float r[6] = {0.f, 0.f, 0.f, 0.f, 0.f, 0.f};
    for (int i = tid; i < nblk; i += BLK) {
        r[0] += partials[0 * nblk + i];
        r[1] += partials[1 * nblk + i];
        r[2] += partials[2 * nblk + i];
        r[3] += partials[3 * nblk + i];
        r[4] += partials[4 * nblk + i];
        r[5] += partials[5 * nblk + i];
    }
    __shared__ float fred[BLK][6];
    for (int j = 0; j < 6; ++j) fred[tid][j] = r[j];
    __syncthreads();
    for (int s = BLK / 2; s > 0; s >>= 1) {
        if (tid < s) {
            for (int j = 0; j < 6; ++j) fred[tid][j] += fred[tid + s][j];
        }
        __syncthreads();
    }
    if (tid == 0) {
        float obj  = fred[0][0] * invBL;
        float wsum = fred[0][1];
        float l1   = fred[0][2] / wsum;
        float giou = fred[0][3] / wsum;
        float ctr  = fred[0][4] / wsum;
        float cls  = fred[0][5] * invBLC;
        out[0] = OBJ_W_C * obj + CTR_W_C * ctr + CLS_W_C * cls + BOX_W_C * l1 + GIOU_W_C * giou;
    }
}

extern "C" void kernel_launch(void* const* d_in, const int* in_sizes, int n_in,
                              void* d_out, int out_size, void* d_ws, size_t ws_size,
                              hipStream_t stream) {
    const float* boxes_xyxy   = (const float*)d_in[0];
    const float* box_deltas   = (const float*)d_in[1];
    const float* class_logits = (const float*)d_in[2];
    const float* objectness   = (const float*)d_in[3];
    const float* centerness   = (const float*)d_in[4];
    const float* locations    = (const float*)d_in[5];
    const float* gt_boxes     = (const float*)d_in[6];
    const int*   gt_labels    = (const int*)d_in[7];
    const int*   gh           = (const int*)d_in[8];
    const int*   gw           = (const int*)d_in[9];

    int L = in_sizes[5] / 2;             // locations: (L,2)
    int B = in_sizes[3] / L;             // objectness: (B,L)
    int C = in_sizes[2] / in_sizes[3];   // class_logits: (B,L,C)
    int M = in_sizes[7] / B;             // gt_labels: (B,M)

    int bpb  = (L + BLK - 1) / BLK;
    int nblk = B * bpb;

    // ws layout (all 64B-aligned):
    //   flags    : B*M*2 int
    //   info     : B*M*8 float
    //   partials : 6*nblk float (per-block sums, SoA)
    //   counter  : 1 int (blocks-done; zeroed by gt_assign_kernel)
    char* p = (char*)d_ws;
    int*   flags  = (int*)p;              p += ((size_t)B * M * 2 * sizeof(int) + 63) / 64 * 64;
    float* info   = (float*)p;            p += ((size_t)B * M * 8 * sizeof(float) + 63) / 64 * 64;
    float* partials = (float*)p;          p += ((size_t)6 * nblk * sizeof(float) + 63) / 64 * 64;
    int*   counter = (int*)p;

    gt_assign_kernel<<<B * M, BLK, 0, stream>>>(locations, gt_boxes, gh, gw,
                                                L, M, info, flags, counter);

    float invBL  = (float)(1.0 / ((double)B * (double)L));
    float invBLC = (float)(1.0 / ((double)B * (double)L * (double)C));

    fused_loss_kernel<<<nblk, BLK, 0, stream>>>(boxes_xyxy, box_deltas,
                                                class_logits, objectness,
                                                centerness, locations,
                                                gt_labels, gh, gw,
                                                L, M, C, bpb, nblk,
                                                info, flags, partials,
                                                counter, (float*)d_out,
                                                invBL, invBLC);
}

// Round 3
// 184.187 us; speedup vs baseline: 1.2467x; 1.2467x over previous
//
#include <hip/hip_runtime.h>
#include <cstdint>
#include <cstddef>
#include <math.h>

#define BOX_W_C  5.0f
#define GIOU_W_C 2.0f
#define OBJ_W_C  1.0f
#define CLS_W_C  1.5f
#define CTR_W_C  0.5f
#define POS_RADIUS_C 1.0f
#define MAXM 128
#define BLK 256

// full focal element: a_t * ce * (1-p_t)^2, alpha=0.25, gamma=2, t in {0,1}
__device__ __forceinline__ float focal_elem(float x, float t) {
    float ax = fabsf(x);
    float e  = __expf(-ax);
    float lg = __logf(1.0f + e);              // log1p(exp(-|x|))
    float ce = fmaxf(x, 0.0f) - x * t + lg;
    float inv = 1.0f / (1.0f + e);
    float p  = (x >= 0.0f) ? inv : e * inv;   // sigmoid
    float p_t = p * t + (1.0f - p) * (1.0f - t);
    float a_t = 0.25f * t + 0.75f * (1.0f - t);
    float om  = 1.0f - p_t;
    return a_t * ce * om * om;
}

// negative-target focal (t = 0): 0.75 * (max(x,0)+log1p(e^-|x|)) * sigmoid(x)^2
__device__ __forceinline__ float focal_neg(float x) {
    float ax = fabsf(x);
    float e  = __expf(-ax);
    float lg = __logf(1.0f + e);
    float ce = fmaxf(x, 0.0f) + lg;
    float inv = 1.0f / (1.0f + e);
    float p  = (x >= 0.0f) ? inv : e * inv;
    return 0.75f * ce * p * p;
}

// focal(x, t=1) - focal(x, t=0), shared transcendentals
__device__ __forceinline__ float focal_pos_correction(float x) {
    float ax = fabsf(x);
    float e  = __expf(-ax);
    float lg = __logf(1.0f + e);
    float relu = fmaxf(x, 0.0f);
    float inv = 1.0f / (1.0f + e);
    float p  = (x >= 0.0f) ? inv : e * inv;
    float om = 1.0f - p;
    float f1 = 0.25f * (relu - x + lg) * om * om;
    float f0 = 0.75f * (relu + lg) * p * p;
    return f1 - f0;
}

__device__ __forceinline__ unsigned long long u64min(unsigned long long a,
                                                     unsigned long long b) {
    return (b < a) ? b : a;
}

// Kernel 1: one block per (b,m). Per-GT: box coords, area, has_candidate,
// fallback best location (first-occurrence argmin via packed (dist,idx) u64
// keys — nonneg float bits are order-monotone, low-32 index breaks ties to
// the smaller index = jnp.argmin first-occurrence semantics).
// NOTE: no atomics / no device-scope fences anywhere in this pipeline —
// an agent-scope ACQ_REL atomic per block (rounds 1-2) forced per-block L2
// maintenance ops on non-coherent XCD L2s and made the fused kernel 4x
// slower (89 us vs <50 us). Separate finalize dispatch is cheaper.
__global__ void gt_assign_kernel(const float* __restrict__ locations,
                                 const float* __restrict__ gt_boxes,
                                 const int* __restrict__ gh_p,
                                 const int* __restrict__ gw_p,
                                 int L, int M,
                                 float* __restrict__ info,
                                 int* __restrict__ flags) {
    int bm  = blockIdx.x;
    int tid = threadIdx.x;

    const float* gb = gt_boxes + (size_t)bm * 4;
    float cx = gb[0], cy = gb[1], w = gb[2], h = gb[3];
    float x1 = cx - w * 0.5f, y1 = cy - h * 0.5f;
    float x2 = cx + w * 0.5f, y2 = cy + h * 0.5f;
    float area = w * h;
    float rx = POS_RADIUS_C / (float)gw_p[0];
    float ry = POS_RADIUS_C / (float)gh_p[0];

    unsigned long long k_in  = ~0ull;   // min over inside_box lanes
    unsigned long long k_all = ~0ull;   // unmasked min
    int any_cand = 0, any_in = 0;

    const float2* loc2 = (const float2*)locations;
    for (int l = tid; l < L; l += BLK) {
        float2 p2 = loc2[l];
        float lx = p2.x, ly = p2.y;
        bool inb = (lx > x1) && (ly > y1) && (lx < x2) && (ly < y2);
        bool inc = (fabsf(lx - cx) <= rx) && (fabsf(ly - cy) <= ry);
        any_cand |= (int)(inb && inc);
        any_in   |= (int)inb;
        float dx = lx - cx, dy = ly - cy;
        float dist = dx * dx + dy * dy;      // finite, nonneg
        unsigned long long kd =
            ((unsigned long long)__float_as_uint(dist) << 32) | (unsigned)l;
        k_all = u64min(k_all, kd);
        if (inb) k_in = u64min(k_in, kd);
    }

    // wave shuffle reduce (64 lanes), no barriers
    for (int off = 32; off > 0; off >>= 1) {
        unsigned long long o1 = __shfl_down(k_in,  off);
        unsigned long long o2 = __shfl_down(k_all, off);
        k_in  = u64min(k_in,  o1);
        k_all = u64min(k_all, o2);
        any_cand |= __shfl_down(any_cand, off);
        any_in   |= __shfl_down(any_in,   off);
    }

    __shared__ unsigned long long sk1[BLK / 64], sk2[BLK / 64];
    __shared__ int sc[BLK / 64], sn[BLK / 64];
    int wid = tid >> 6;
    if ((tid & 63) == 0) {
        sk1[wid] = k_in; sk2[wid] = k_all;
        sc[wid] = any_cand; sn[wid] = any_in;
    }
    __syncthreads();
    if (tid == 0) {
        for (int w2 = 1; w2 < BLK / 64; ++w2) {
            k_in  = u64min(k_in,  sk1[w2]);
            k_all = u64min(k_all, sk2[w2]);
            any_cand |= sc[w2];
            any_in   |= sn[w2];
        }
        int best = any_in ? (int)(k_in & 0xffffffffu) : (int)(k_all & 0xffffffffu);
        flags[bm * 2]     = any_cand;
        flags[bm * 2 + 1] = best;
        float* oi = info + (size_t)bm * 8;
        oi[0] = x1; oi[1] = y1; oi[2] = x2; oi[3] = y2;
        oi[4] = cx; oi[5] = cy; oi[6] = area; oi[7] = 0.0f;
    }
}

// Kernel 2 (fused): block = 256 consecutive locations of one batch image.
// Phase 1: per-location assignment + obj focal + box/GIoU/ctr losses.
// Phase 2: class focal = flat streaming sum of focal_neg over the block's
// contiguous 256*C logits (plain cached loads — nt loads measured 4x slower
// in round 1 when combined with the atomic tail; plain loads + no atomics
// is the proven-fast round-0 configuration).
// Per-block partials stored to private slots (no atomics).
__global__ void fused_loss_kernel(const float* __restrict__ boxes_xyxy,
                                  const float* __restrict__ box_deltas,
                                  const float* __restrict__ class_logits,
                                  const float* __restrict__ objectness,
                                  const float* __restrict__ centerness,
                                  const float* __restrict__ locations,
                                  const int* __restrict__ gt_labels,
                                  const int* __restrict__ gh_p,
                                  const int* __restrict__ gw_p,
                                  int L, int M, int C, int bpb, int nblk,
                                  const float* __restrict__ info,
                                  const int* __restrict__ flags,
                                  float* __restrict__ partials) {
    __shared__ float s_x1[MAXM], s_y1[MAXM], s_x2[MAXM], s_y2[MAXM];
    __shared__ float s_cx[MAXM], s_cy[MAXM], s_area[MAXM];
    __shared__ int   s_lab[MAXM], s_hc[MAXM], s_best[MAXM];

    int b    = blockIdx.x / bpb;
    int lblk = blockIdx.x % bpb;
    int tid  = threadIdx.x;

    if (tid < M && tid < MAXM) {
        int bm = b * M + tid;
        const float* oi = info + (size_t)bm * 8;
        s_x1[tid] = oi[0]; s_y1[tid] = oi[1]; s_x2[tid] = oi[2]; s_y2[tid] = oi[3];
        s_cx[tid] = oi[4]; s_cy[tid] = oi[5]; s_area[tid] = oi[6];
        s_lab[tid]  = gt_labels[bm];
        s_hc[tid]   = flags[bm * 2];
        s_best[tid] = flags[bm * 2 + 1];
    }
    __syncthreads();

    int l0 = lblk * BLK;
    int l  = l0 + tid;
    float a_obj = 0.f, a_w = 0.f, a_l1 = 0.f, a_giou = 0.f, a_ctr = 0.f;
    float a_cls = 0.f;
    int mylab = -1;

    if (l < L) {
        size_t bl = (size_t)b * L + l;
        const float2* loc2 = (const float2*)locations;
        float2 p2 = loc2[l];
        float lx = p2.x, ly = p2.y;
        float rx = POS_RADIUS_C / (float)gw_p[0];
        float ry = POS_RADIUS_C / (float)gh_p[0];

        float minc = INFINITY;
        int   asg  = -1;
        for (int m = 0; m < M; ++m) {
            bool cand;
            if (s_hc[m]) {
                cand = (lx > s_x1[m]) && (ly > s_y1[m]) && (lx < s_x2[m]) && (ly < s_y2[m])
                    && (fabsf(lx - s_cx[m]) <= rx) && (fabsf(ly - s_cy[m]) <= ry);
            } else {
                cand = (l == s_best[m]);
            }
            if (cand && (s_area[m] < minc)) { minc = s_area[m]; asg = m; }  // first-min wins
        }
        bool  pos   = (asg >= 0);
        float pos_f = pos ? 1.0f : 0.0f;
        mylab = pos ? s_lab[asg] : -1;

        a_obj = focal_elem(objectness[bl], pos_f);

        if (pos) {
            float ax1 = s_x1[asg], ay1 = s_y1[asg], ax2 = s_x2[asg], ay2 = s_y2[asg];
            float ltl = fmaxf(lx - ax1, 1e-6f);
            float ltt = fmaxf(ly - ay1, 1e-6f);
            float ltr = fmaxf(ax2 - lx, 1e-6f);
            float ltb = fmaxf(ay2 - ly, 1e-6f);
            float hor = fminf(ltl, ltr) / fmaxf(fmaxf(ltl, ltr), 1e-6f);
            float ver = fminf(ltt, ltb) / fmaxf(fmaxf(ltt, ltb), 1e-6f);
            float ctr_t = sqrtf(fmaxf(hor * ver, 0.0f));
            float wgt = fmaxf(ctr_t, 0.1f);
            a_w = wgt;

            // smooth-L1 (beta = 0.1), mean over 4 coords
            const float4 bd = *(const float4*)(box_deltas + bl * 4);
            float d0 = fabsf(bd.x - ltl), d1 = fabsf(bd.y - ltt);
            float d2 = fabsf(bd.z - ltr), d3 = fabsf(bd.w - ltb);
            float l1s = ((d0 < 0.1f) ? (0.5f * d0 * d0 / 0.1f) : (d0 - 0.05f))
                      + ((d1 < 0.1f) ? (0.5f * d1 * d1 / 0.1f) : (d1 - 0.05f))
                      + ((d2 < 0.1f) ? (0.5f * d2 * d2 / 0.1f) : (d2 - 0.05f))
                      + ((d3 < 0.1f) ? (0.5f * d3 * d3 / 0.1f) : (d3 - 0.05f));
            a_l1 = (l1s * 0.25f) * wgt;

            // GIoU
            const float4 pb = *(const float4*)(boxes_xyxy + bl * 4);
            float px1 = pb.x, py1 = pb.y, px2 = pb.z, py2 = pb.w;
            float ilx = fmaxf(px1, ax1), ily = fmaxf(py1, ay1);
            float irx = fminf(px2, ax2), iry = fminf(py2, ay2);
            float iw = fmaxf(irx - ilx, 0.f), ih = fmaxf(iry - ily, 0.f);
            float inter = iw * ih;
            float ap = fmaxf(px2 - px1, 0.f) * fmaxf(py2 - py1, 0.f);
            float ag = fmaxf(ax2 - ax1, 0.f) * fmaxf(ay2 - ay1, 0.f);
            float un = ap + ag - inter;
            float iou = inter / fmaxf(un, 1e-6f);
            float hlx = fminf(px1, ax1), hly = fminf(py1, ay1);
            float hrx = fmaxf(px2, ax2), hry = fmaxf(py2, ay2);
            float hw = fmaxf(hrx - hlx, 0.f), hh = fmaxf(hry - hly, 0.f);
            float hull = hw * hh;
            float giou = iou - (hull - un) / fmaxf(hull, 1e-6f);
            a_giou = (1.0f - giou) * wgt;

            // centerness BCE
            float xc = centerness[bl];
            float bce = fmaxf(xc, 0.f) - xc * ctr_t + __logf(1.0f + __expf(-fabsf(xc)));
            a_ctr = bce * wgt;
        }

        // positive-class correction for this thread's own row (rare path)
        if (mylab >= 0) {
            float xl = class_logits[bl * (size_t)C + mylab];
            a_cls += focal_pos_correction(xl);
        }
    }

    // Phase 2: flat streaming focal_neg over rows [l0, l0+nrows) x C.
    {
        int nrows = L - l0; if (nrows > BLK) nrows = BLK;
        int C4 = C >> 2;
        if (C4 > 0) {
            const float4* cl4 = (const float4*)(class_logits + ((size_t)b * L + l0) * C);
            int total4 = nrows * C4;
            for (int it = tid; it < total4; it += BLK) {
                float4 v = cl4[it];
                a_cls += focal_neg(v.x);
                a_cls += focal_neg(v.y);
                a_cls += focal_neg(v.z);
                a_cls += focal_neg(v.w);
            }
        }
        int crem = C - (C4 << 2);              // leftover classes (C % 4) — rare path
        if (crem) {
            const float* base = class_logits + ((size_t)b * L + l0) * C + (C4 << 2);
            for (int rr = tid; rr < nrows; rr += BLK)
                for (int j = 0; j < crem; ++j)
                    a_cls += focal_neg(base[(size_t)rr * C + j]);
        }
    }

    // wave shuffle reduce, LDS across waves, thread 0 stores 6 partials
    for (int off = 32; off > 0; off >>= 1) {
        a_obj  += __shfl_down(a_obj,  off);
        a_w    += __shfl_down(a_w,    off);
        a_l1   += __shfl_down(a_l1,   off);
        a_giou += __shfl_down(a_giou, off);
        a_ctr  += __shfl_down(a_ctr,  off);
        a_cls  += __shfl_down(a_cls,  off);
    }
    __shared__ float red[BLK / 64][6];
    int wid = tid >> 6;
    if ((tid & 63) == 0) {
        red[wid][0] = a_obj; red[wid][1] = a_w; red[wid][2] = a_l1;
        red[wid][3] = a_giou; red[wid][4] = a_ctr; red[wid][5] = a_cls;
    }
    __syncthreads();
    if (tid == 0) {
        float r0 = 0.f, r1 = 0.f, r2 = 0.f, r3 = 0.f, r4 = 0.f, r5 = 0.f;
        for (int w2 = 0; w2 < BLK / 64; ++w2) {
            r0 += red[w2][0]; r1 += red[w2][1]; r2 += red[w2][2];
            r3 += red[w2][3]; r4 += red[w2][4]; r5 += red[w2][5];
        }
        int blk = (int)blockIdx.x;
        partials[0 * nblk + blk] = r0;   // obj
        partials[1 * nblk + blk] = r1;   // wsum
        partials[2 * nblk + blk] = r2;   // l1
        partials[3 * nblk + blk] = r3;   // giou
        partials[4 * nblk + blk] = r4;   // ctr
        partials[5 * nblk + blk] = r5;   // cls
    }
}

// Kernel 3: single-block deterministic reduction over all partials + combine.
__global__ void finalize_kernel(const float* __restrict__ partials, int nblk,
                                float* __restrict__ out,
                                float invBL, float invBLC) {
    int tid = threadIdx.x;
    float r[6] = {0.f, 0.f, 0.f, 0.f, 0.f, 0.f};
    for (int i = tid; i < nblk; i += blockDim.x) {
        r[0] += partials[0 * nblk + i];
        r[1] += partials[1 * nblk + i];
        r[2] += partials[2 * nblk + i];
        r[3] += partials[3 * nblk + i];
        r[4] += partials[4 * nblk + i];
        r[5] += partials[5 * nblk + i];
    }
    __shared__ float red[256][6];
    for (int j = 0; j < 6; ++j) red[tid][j] = r[j];
    __syncthreads();
    for (int s = (int)blockDim.x / 2; s > 0; s >>= 1) {
        if (tid < s) {
            for (int j = 0; j < 6; ++j) red[tid][j] += red[tid + s][j];
        }
        __syncthreads();
    }
    if (tid == 0) {
        float obj  = red[0][0] * invBL;
        float wsum = red[0][1];
        float l1   = red[0][2] / wsum;
        float giou = red[0][3] / wsum;
        float ctr  = red[0][4] / wsum;
        float cls  = red[0][5] * invBLC;
        out[0] = OBJ_W_C * obj + CTR_W_C * ctr + CLS_W_C * cls + BOX_W_C * l1 + GIOU_W_C * giou;
    }
}

extern "C" void kernel_launch(void* const* d_in, const int* in_sizes, int n_in,
                              void* d_out, int out_size, void* d_ws, size_t ws_size,
                              hipStream_t stream) {
    const float* boxes_xyxy   = (const float*)d_in[0];
    const float* box_deltas   = (const float*)d_in[1];
    const float* class_logits = (const float*)d_in[2];
    const float* objectness   = (const float*)d_in[3];
    const float* centerness   = (const float*)d_in[4];
    const float* locations    = (const float*)d_in[5];
    const float* gt_boxes     = (const float*)d_in[6];
    const int*   gt_labels    = (const int*)d_in[7];
    const int*   gh           = (const int*)d_in[8];
    const int*   gw           = (const int*)d_in[9];

    int L = in_sizes[5] / 2;             // locations: (L,2)
    int B = in_sizes[3] / L;             // objectness: (B,L)
    int C = in_sizes[2] / in_sizes[3];   // class_logits: (B,L,C)
    int M = in_sizes[7] / B;             // gt_labels: (B,M)

    int bpb  = (L + BLK - 1) / BLK;
    int nblk = B * bpb;

    // ws layout (all 64B-aligned):
    //   flags    : B*M*2 int
    //   info     : B*M*8 float
    //   partials : 6*nblk float (per-block sums, SoA)
    char* p = (char*)d_ws;
    int*   flags  = (int*)p;              p += ((size_t)B * M * 2 * sizeof(int) + 63) / 64 * 64;
    float* info   = (float*)p;            p += ((size_t)B * M * 8 * sizeof(float) + 63) / 64 * 64;
    float* partials = (float*)p;

    gt_assign_kernel<<<B * M, BLK, 0, stream>>>(locations, gt_boxes, gh, gw,
                                                L, M, info, flags);

    fused_loss_kernel<<<nblk, BLK, 0, stream>>>(boxes_xyxy, box_deltas,
                                                class_logits, objectness,
                                                centerness, locations,
                                                gt_labels, gh, gw,
                                                L, M, C, bpb, nblk,
                                                info, flags, partials);

    float invBL  = (float)(1.0 / ((double)B * (double)L));
    float invBLC = (float)(1.0 / ((double)B * (double)L * (double)C));
    finalize_kernel<<<1, 256, 0, stream>>>(partials, nblk, (float*)d_out,
                                           invBL, invBLC);
}

// Round 4
// 168.453 us; speedup vs baseline: 1.3631x; 1.0934x over previous
//
#include <hip/hip_runtime.h>
#include <cstdint>
#include <cstddef>
#include <math.h>

#define BOX_W_C  5.0f
#define GIOU_W_C 2.0f
#define OBJ_W_C  1.0f
#define CLS_W_C  1.5f
#define CTR_W_C  0.5f
#define POS_RADIUS_C 1.0f
#define MAXM 128
#define ROWS 256          // locations per fused block (phase-1 width)
#define FBLK 512          // fused block threads (phase-2 width, 8 waves)
#define GBLK 512          // gt_assign block threads

// full focal element: a_t * ce * (1-p_t)^2, alpha=0.25, gamma=2, t in {0,1}
__device__ __forceinline__ float focal_elem(float x, float t) {
    float ax = fabsf(x);
    float e  = __expf(-ax);
    float lg = __logf(1.0f + e);              // log1p(exp(-|x|))
    float ce = fmaxf(x, 0.0f) - x * t + lg;
    float inv = 1.0f / (1.0f + e);
    float p  = (x >= 0.0f) ? inv : e * inv;   // sigmoid
    float p_t = p * t + (1.0f - p) * (1.0f - t);
    float a_t = 0.25f * t + 0.75f * (1.0f - t);
    float om  = 1.0f - p_t;
    return a_t * ce * om * om;
}

// negative-target focal (t = 0): 0.75 * (max(x,0)+log1p(e^-|x|)) * sigmoid(x)^2
__device__ __forceinline__ float focal_neg(float x) {
    float ax = fabsf(x);
    float e  = __expf(-ax);
    float lg = __logf(1.0f + e);
    float ce = fmaxf(x, 0.0f) + lg;
    float inv = 1.0f / (1.0f + e);
    float p  = (x >= 0.0f) ? inv : e * inv;
    return 0.75f * ce * p * p;
}

// focal(x, t=1) - focal(x, t=0), shared transcendentals
__device__ __forceinline__ float focal_pos_correction(float x) {
    float ax = fabsf(x);
    float e  = __expf(-ax);
    float lg = __logf(1.0f + e);
    float relu = fmaxf(x, 0.0f);
    float inv = 1.0f / (1.0f + e);
    float p  = (x >= 0.0f) ? inv : e * inv;
    float om = 1.0f - p;
    float f1 = 0.25f * (relu - x + lg) * om * om;
    float f0 = 0.75f * (relu + lg) * p * p;
    return f1 - f0;
}

__device__ __forceinline__ unsigned long long u64min(unsigned long long a,
                                                     unsigned long long b) {
    return (b < a) ? b : a;
}

// Kernel 1: one block per (b,m). Per-GT: box coords, area, has_candidate,
// fallback best location (first-occurrence argmin via packed (dist,idx) u64
// keys — nonneg float bits are order-monotone, low-32 index breaks ties to
// the smaller index = jnp.argmin first-occurrence semantics).
// 512 threads: 2 blocks/CU, latency-sensitive L2-resident scan needs the TLP
// (256 threads measured ~8 us slower end-to-end, round 3).
// NOTE: no atomics / no device-scope fences anywhere in this pipeline —
// an agent-scope ACQ_REL atomic per block (rounds 1-2) forced per-block L2
// maintenance ops on non-coherent XCD L2s and made the fused kernel 4x
// slower (89 us vs <50 us). Separate finalize dispatch is cheaper.
__global__ void gt_assign_kernel(const float* __restrict__ locations,
                                 const float* __restrict__ gt_boxes,
                                 const int* __restrict__ gh_p,
                                 const int* __restrict__ gw_p,
                                 int L, int M,
                                 float* __restrict__ info,
                                 int* __restrict__ flags) {
    int bm  = blockIdx.x;
    int tid = threadIdx.x;

    const float* gb = gt_boxes + (size_t)bm * 4;
    float cx = gb[0], cy = gb[1], w = gb[2], h = gb[3];
    float x1 = cx - w * 0.5f, y1 = cy - h * 0.5f;
    float x2 = cx + w * 0.5f, y2 = cy + h * 0.5f;
    float area = w * h;
    float rx = POS_RADIUS_C / (float)gw_p[0];
    float ry = POS_RADIUS_C / (float)gh_p[0];

    unsigned long long k_in  = ~0ull;   // min over inside_box lanes
    unsigned long long k_all = ~0ull;   // unmasked min
    int any_cand = 0, any_in = 0;

    const float2* loc2 = (const float2*)locations;
    for (int l = tid; l < L; l += GBLK) {
        float2 p2 = loc2[l];
        float lx = p2.x, ly = p2.y;
        bool inb = (lx > x1) && (ly > y1) && (lx < x2) && (ly < y2);
        bool inc = (fabsf(lx - cx) <= rx) && (fabsf(ly - cy) <= ry);
        any_cand |= (int)(inb && inc);
        any_in   |= (int)inb;
        float dx = lx - cx, dy = ly - cy;
        float dist = dx * dx + dy * dy;      // finite, nonneg
        unsigned long long kd =
            ((unsigned long long)__float_as_uint(dist) << 32) | (unsigned)l;
        k_all = u64min(k_all, kd);
        if (inb) k_in = u64min(k_in, kd);
    }

    // wave shuffle reduce (64 lanes), no barriers
    for (int off = 32; off > 0; off >>= 1) {
        unsigned long long o1 = __shfl_down(k_in,  off);
        unsigned long long o2 = __shfl_down(k_all, off);
        k_in  = u64min(k_in,  o1);
        k_all = u64min(k_all, o2);
        any_cand |= __shfl_down(any_cand, off);
        any_in   |= __shfl_down(any_in,   off);
    }

    __shared__ unsigned long long sk1[GBLK / 64], sk2[GBLK / 64];
    __shared__ int sc[GBLK / 64], sn[GBLK / 64];
    int wid = tid >> 6;
    if ((tid & 63) == 0) {
        sk1[wid] = k_in; sk2[wid] = k_all;
        sc[wid] = any_cand; sn[wid] = any_in;
    }
    __syncthreads();
    if (tid == 0) {
        for (int w2 = 1; w2 < GBLK / 64; ++w2) {
            k_in  = u64min(k_in,  sk1[w2]);
            k_all = u64min(k_all, sk2[w2]);
            any_cand |= sc[w2];
            any_in   |= sn[w2];
        }
        int best = any_in ? (int)(k_in & 0xffffffffu) : (int)(k_all & 0xffffffffu);
        flags[bm * 2]     = any_cand;
        flags[bm * 2 + 1] = best;
        float* oi = info + (size_t)bm * 8;
        oi[0] = x1; oi[1] = y1; oi[2] = x2; oi[3] = y2;
        oi[4] = cx; oi[5] = cy; oi[6] = area; oi[7] = 0.0f;
    }
}

// Kernel 2 (fused): 512 threads per block, block covers 256 consecutive
// locations of one batch image.
// Phase 1 (threads 0..255): per-location assignment + obj focal +
// box/GIoU/ctr losses.
// Phase 2 (all 512 threads): class focal = flat streaming sum of focal_neg
// over the block's contiguous 256*C logits (plain cached loads; LLC-resident
// inputs). 512 threads -> 8 waves/block x 4 blocks/CU = 32 waves/CU (100%
// occupancy ceiling) to hide LLC latency on the 84 MB logits stream; at 256
// threads the kernel sat at ~30% occupancy, latency-limited.
// Per-block partials stored to private slots (no atomics).
__global__ void __launch_bounds__(FBLK)
fused_loss_kernel(const float* __restrict__ boxes_xyxy,
                  const float* __restrict__ box_deltas,
                  const float* __restrict__ class_logits,
                  const float* __restrict__ objectness,
                  const float* __restrict__ centerness,
                  const float* __restrict__ locations,
                  const int* __restrict__ gt_labels,
                  const int* __restrict__ gh_p,
                  const int* __restrict__ gw_p,
                  int L, int M, int C, int bpb, int nblk,
                  const float* __restrict__ info,
                  const int* __restrict__ flags,
                  float* __restrict__ partials) {
    __shared__ float s_x1[MAXM], s_y1[MAXM], s_x2[MAXM], s_y2[MAXM];
    __shared__ float s_cx[MAXM], s_cy[MAXM], s_area[MAXM];
    __shared__ int   s_lab[MAXM], s_hc[MAXM], s_best[MAXM];

    int b    = blockIdx.x / bpb;
    int lblk = blockIdx.x % bpb;
    int tid  = threadIdx.x;

    if (tid < M && tid < MAXM) {
        int bm = b * M + tid;
        const float* oi = info + (size_t)bm * 8;
        s_x1[tid] = oi[0]; s_y1[tid] = oi[1]; s_x2[tid] = oi[2]; s_y2[tid] = oi[3];
        s_cx[tid] = oi[4]; s_cy[tid] = oi[5]; s_area[tid] = oi[6];
        s_lab[tid]  = gt_labels[bm];
        s_hc[tid]   = flags[bm * 2];
        s_best[tid] = flags[bm * 2 + 1];
    }
    __syncthreads();

    int l0 = lblk * ROWS;
    int l  = l0 + tid;
    float a_obj = 0.f, a_w = 0.f, a_l1 = 0.f, a_giou = 0.f, a_ctr = 0.f;
    float a_cls = 0.f;

    if (tid < ROWS && l < L) {
        size_t bl = (size_t)b * L + l;
        const float2* loc2 = (const float2*)locations;
        float2 p2 = loc2[l];
        float lx = p2.x, ly = p2.y;
        float rx = POS_RADIUS_C / (float)gw_p[0];
        float ry = POS_RADIUS_C / (float)gh_p[0];

        float minc = INFINITY;
        int   asg  = -1;
        for (int m = 0; m < M; ++m) {
            bool cand;
            if (s_hc[m]) {
                cand = (lx > s_x1[m]) && (ly > s_y1[m]) && (lx < s_x2[m]) && (ly < s_y2[m])
                    && (fabsf(lx - s_cx[m]) <= rx) && (fabsf(ly - s_cy[m]) <= ry);
            } else {
                cand = (l == s_best[m]);
            }
            if (cand && (s_area[m] < minc)) { minc = s_area[m]; asg = m; }  // first-min wins
        }
        bool  pos   = (asg >= 0);
        float pos_f = pos ? 1.0f : 0.0f;
        int mylab = pos ? s_lab[asg] : -1;

        a_obj = focal_elem(objectness[bl], pos_f);

        if (pos) {
            float ax1 = s_x1[asg], ay1 = s_y1[asg], ax2 = s_x2[asg], ay2 = s_y2[asg];
            float ltl = fmaxf(lx - ax1, 1e-6f);
            float ltt = fmaxf(ly - ay1, 1e-6f);
            float ltr = fmaxf(ax2 - lx, 1e-6f);
            float ltb = fmaxf(ay2 - ly, 1e-6f);
            float hor = fminf(ltl, ltr) / fmaxf(fmaxf(ltl, ltr), 1e-6f);
            float ver = fminf(ltt, ltb) / fmaxf(fmaxf(ltt, ltb), 1e-6f);
            float ctr_t = sqrtf(fmaxf(hor * ver, 0.0f));
            float wgt = fmaxf(ctr_t, 0.1f);
            a_w = wgt;

            // smooth-L1 (beta = 0.1), mean over 4 coords
            const float4 bd = *(const float4*)(box_deltas + bl * 4);
            float d0 = fabsf(bd.x - ltl), d1 = fabsf(bd.y - ltt);
            float d2 = fabsf(bd.z - ltr), d3 = fabsf(bd.w - ltb);
            float l1s = ((d0 < 0.1f) ? (0.5f * d0 * d0 / 0.1f) : (d0 - 0.05f))
                      + ((d1 < 0.1f) ? (0.5f * d1 * d1 / 0.1f) : (d1 - 0.05f))
                      + ((d2 < 0.1f) ? (0.5f * d2 * d2 / 0.1f) : (d2 - 0.05f))
                      + ((d3 < 0.1f) ? (0.5f * d3 * d3 / 0.1f) : (d3 - 0.05f));
            a_l1 = (l1s * 0.25f) * wgt;

            // GIoU
            const float4 pb = *(const float4*)(boxes_xyxy + bl * 4);
            float px1 = pb.x, py1 = pb.y, px2 = pb.z, py2 = pb.w;
            float ilx = fmaxf(px1, ax1), ily = fmaxf(py1, ay1);
            float irx = fminf(px2, ax2), iry = fminf(py2, ay2);
            float iw = fmaxf(irx - ilx, 0.f), ih = fmaxf(iry - ily, 0.f);
            float inter = iw * ih;
            float ap = fmaxf(px2 - px1, 0.f) * fmaxf(py2 - py1, 0.f);
            float ag = fmaxf(ax2 - ax1, 0.f) * fmaxf(ay2 - ay1, 0.f);
            float un = ap + ag - inter;
            float iou = inter / fmaxf(un, 1e-6f);
            float hlx = fminf(px1, ax1), hly = fminf(py1, ay1);
            float hrx = fmaxf(px2, ax2), hry = fmaxf(py2, ay2);
            float hw = fmaxf(hrx - hlx, 0.f), hh = fmaxf(hry - hly, 0.f);
            float hull = hw * hh;
            float giou = iou - (hull - un) / fmaxf(hull, 1e-6f);
            a_giou = (1.0f - giou) * wgt;

            // centerness BCE
            float xc = centerness[bl];
            float bce = fmaxf(xc, 0.f) - xc * ctr_t + __logf(1.0f + __expf(-fabsf(xc)));
            a_ctr = bce * wgt;
        }

        // positive-class correction for this thread's own row (rare path)
        if (mylab >= 0) {
            float xl = class_logits[bl * (size_t)C + mylab];
            a_cls += focal_pos_correction(xl);
        }
    }

    // Phase 2: flat streaming focal_neg over rows [l0, l0+nrows) x C,
    // all FBLK threads.
    {
        int nrows = L - l0; if (nrows > ROWS) nrows = ROWS;
        int C4 = C >> 2;
        if (C4 > 0) {
            const float4* cl4 = (const float4*)(class_logits + ((size_t)b * L + l0) * C);
            int total4 = nrows * C4;
            for (int it = tid; it < total4; it += FBLK) {
                float4 v = cl4[it];
                a_cls += focal_neg(v.x);
                a_cls += focal_neg(v.y);
                a_cls += focal_neg(v.z);
                a_cls += focal_neg(v.w);
            }
        }
        int crem = C - (C4 << 2);              // leftover classes (C % 4) — rare path
        if (crem) {
            const float* base = class_logits + ((size_t)b * L + l0) * C + (C4 << 2);
            for (int rr = tid; rr < nrows; rr += FBLK)
                for (int j = 0; j < crem; ++j)
                    a_cls += focal_neg(base[(size_t)rr * C + j]);
        }
    }

    // wave shuffle reduce, LDS across waves, thread 0 stores 6 partials
    for (int off = 32; off > 0; off >>= 1) {
        a_obj  += __shfl_down(a_obj,  off);
        a_w    += __shfl_down(a_w,    off);
        a_l1   += __shfl_down(a_l1,   off);
        a_giou += __shfl_down(a_giou, off);
        a_ctr  += __shfl_down(a_ctr,  off);
        a_cls  += __shfl_down(a_cls,  off);
    }
    __shared__ float red[FBLK / 64][6];
    int wid = tid >> 6;
    if ((tid & 63) == 0) {
        red[wid][0] = a_obj; red[wid][1] = a_w; red[wid][2] = a_l1;
        red[wid][3] = a_giou; red[wid][4] = a_ctr; red[wid][5] = a_cls;
    }
    __syncthreads();
    if (tid == 0) {
        float r0 = 0.f, r1 = 0.f, r2 = 0.f, r3 = 0.f, r4 = 0.f, r5 = 0.f;
        for (int w2 = 0; w2 < FBLK / 64; ++w2) {
            r0 += red[w2][0]; r1 += red[w2][1]; r2 += red[w2][2];
            r3 += red[w2][3]; r4 += red[w2][4]; r5 += red[w2][5];
        }
        int blk = (int)blockIdx.x;
        partials[0 * nblk + blk] = r0;   // obj
        partials[1 * nblk + blk] = r1;   // wsum
        partials[2 * nblk + blk] = r2;   // l1
        partials[3 * nblk + blk] = r3;   // giou
        partials[4 * nblk + blk] = r4;   // ctr
        partials[5 * nblk + blk] = r5;   // cls
    }
}

// Kernel 3: single-block deterministic reduction over all partials + combine.
__global__ void finalize_kernel(const float* __restrict__ partials, int nblk,
                                float* __restrict__ out,
                                float invBL, float invBLC) {
    int tid = threadIdx.x;
    float r[6] = {0.f, 0.f, 0.f, 0.f, 0.f, 0.f};
    for (int i = tid; i < nblk; i += blockDim.x) {
        r[0] += partials[0 * nblk + i];
        r[1] += partials[1 * nblk + i];
        r[2] += partials[2 * nblk + i];
        r[3] += partials[3 * nblk + i];
        r[4] += partials[4 * nblk + i];
        r[5] += partials[5 * nblk + i];
    }
    __shared__ float red[256][6];
    for (int j = 0; j < 6; ++j) red[tid][j] = r[j];
    __syncthreads();
    for (int s = (int)blockDim.x / 2; s > 0; s >>= 1) {
        if (tid < s) {
            for (int j = 0; j < 6; ++j) red[tid][j] += red[tid + s][j];
        }
        __syncthreads();
    }
    if (tid == 0) {
        float obj  = red[0][0] * invBL;
        float wsum = red[0][1];
        float l1   = red[0][2] / wsum;
        float giou = red[0][3] / wsum;
        float ctr  = red[0][4] / wsum;
        float cls  = red[0][5] * invBLC;
        out[0] = OBJ_W_C * obj + CTR_W_C * ctr + CLS_W_C * cls + BOX_W_C * l1 + GIOU_W_C * giou;
    }
}

extern "C" void kernel_launch(void* const* d_in, const int* in_sizes, int n_in,
                              void* d_out, int out_size, void* d_ws, size_t ws_size,
                              hipStream_t stream) {
    const float* boxes_xyxy   = (const float*)d_in[0];
    const float* box_deltas   = (const float*)d_in[1];
    const float* class_logits = (const float*)d_in[2];
    const float* objectness   = (const float*)d_in[3];
    const float* centerness   = (const float*)d_in[4];
    const float* locations    = (const float*)d_in[5];
    const float* gt_boxes     = (const float*)d_in[6];
    const int*   gt_labels    = (const int*)d_in[7];
    const int*   gh           = (const int*)d_in[8];
    const int*   gw           = (const int*)d_in[9];

    int L = in_sizes[5] / 2;             // locations: (L,2)
    int B = in_sizes[3] / L;             // objectness: (B,L)
    int C = in_sizes[2] / in_sizes[3];   // class_logits: (B,L,C)
    int M = in_sizes[7] / B;             // gt_labels: (B,M)

    int bpb  = (L + ROWS - 1) / ROWS;
    int nblk = B * bpb;

    // ws layout (all 64B-aligned):
    //   flags    : B*M*2 int
    //   info     : B*M*8 float
    //   partials : 6*nblk float (per-block sums, SoA)
    char* p = (char*)d_ws;
    int*   flags  = (int*)p;              p += ((size_t)B * M * 2 * sizeof(int) + 63) / 64 * 64;
    float* info   = (float*)p;            p += ((size_t)B * M * 8 * sizeof(float) + 63) / 64 * 64;
    float* partials = (float*)p;

    gt_assign_kernel<<<B * M, GBLK, 0, stream>>>(locations, gt_boxes, gh, gw,
                                                 L, M, info, flags);

    fused_loss_kernel<<<nblk, FBLK, 0, stream>>>(boxes_xyxy, box_deltas,
                                                 class_logits, objectness,
                                                 centerness, locations,
                                                 gt_labels, gh, gw,
                                                 L, M, C, bpb, nblk,
                                                 info, flags, partials);

    float invBL  = (float)(1.0 / ((double)B * (double)L));
    float invBLC = (float)(1.0 / ((double)B * (double)L * (double)C));
    finalize_kernel<<<1, 256, 0, stream>>>(partials, nblk, (float*)d_out,
                                           invBL, invBLC);
}